// Round 13
// baseline (139.475 us; speedup 1.0000x reference)
//
#include <hip/hip_runtime.h>
#include <hip/hip_bf16.h>

// B=16, T=32, N=8192. pred/cenp: [B,T,N,3] f32; dofs: [B,T,4] f32; ptrans: [B,T,3] f32.
// out: [B,T,N,3] f32.  out = (pred - cenp) @ R(q) + ptrans + cenp   (row-vector convention)
//
// Round 5: LDS-staged tile so every GLOBAL access is lane-contiguous float4
// (round-4 version had 48B lane stride inside each dwordx4 -> 3x line-visits).
// LDS compute-phase reads are scalar f32 at stride-3 floats: gcd(3,32)=1 ->
// bank-bijective over 32 lanes, 2-way over 64 (free).

#define BLOCK 256
#define PTS_PER_THREAD 4
#define TILE_PTS (BLOCK * PTS_PER_THREAD)   // 1024 points per tile (8 tiles per bt since N=8192)
#define TILE_F (TILE_PTS * 3)               // 3072 floats = 12 KB
#define TILE_F4 (TILE_F / 4)                // 768 float4

__global__ __launch_bounds__(256) void tooth_assembler_kernel(
    const float* __restrict__ pred,
    const float* __restrict__ cenp,
    const float* __restrict__ dofs,
    const float* __restrict__ ptrans,
    float* __restrict__ out,
    int n_tiles)
{
    __shared__ float sp[TILE_F];   // pred tile, overwritten in-place with output
    __shared__ float sc[TILE_F];   // cenp tile

    const int tid = threadIdx.x;
    float4* sp4 = reinterpret_cast<float4*>(sp);
    float4* sc4 = reinterpret_cast<float4*>(sc);

    for (int tile = blockIdx.x; tile < n_tiles; tile += gridDim.x) {
        // tile -> (b,t): 8 tiles per bt (8192/1024). Uniform across the block.
        int bt = tile >> 3;

        // Quaternion -> rotation matrix (real-part-first: r,i,j,k); uniform data.
        const float4 q = *reinterpret_cast<const float4*>(dofs + bt * 4);
        float r = q.x, i = q.y, j = q.z, k = q.w;
        float two_s = 2.0f / (r * r + i * i + j * j + k * k);
        float R00 = 1.0f - two_s * (j * j + k * k);
        float R01 = two_s * (i * j - k * r);
        float R02 = two_s * (i * k + j * r);
        float R10 = two_s * (i * j + k * r);
        float R11 = 1.0f - two_s * (i * i + k * k);
        float R12 = two_s * (j * k - i * r);
        float R20 = two_s * (i * k - j * r);
        float R21 = two_s * (j * k + i * r);
        float R22 = 1.0f - two_s * (i * i + j * j);
        float tx = ptrans[bt * 3 + 0];
        float ty = ptrans[bt * 3 + 1];
        float tz = ptrans[bt * 3 + 2];

        size_t base4 = (size_t)tile * TILE_F4;
        const float4* p4 = reinterpret_cast<const float4*>(pred) + base4;
        const float4* c4 = reinterpret_cast<const float4*>(cenp) + base4;
        float4* o4 = reinterpret_cast<float4*>(out) + base4;

        // Stage in: lane-contiguous float4 (16B/lane, fully coalesced).
#pragma unroll
        for (int s = 0; s < 3; ++s) {
            sp4[tid + BLOCK * s] = p4[tid + BLOCK * s];
            sc4[tid + BLOCK * s] = c4[tid + BLOCK * s];
        }
        __syncthreads();

        // Compute: thread handles points tid + 256*m -> stride-3-float LDS reads,
        // conflict-free. Output overwrites sp in-place (same thread, same point).
#pragma unroll
        for (int m = 0; m < PTS_PER_THREAD; ++m) {
            int e = 3 * (tid + BLOCK * m);
            float cx = sc[e], cy = sc[e + 1], cz = sc[e + 2];
            float x = sp[e] - cx, y = sp[e + 1] - cy, z = sp[e + 2] - cz;
            sp[e]     = x * R00 + y * R10 + z * R20 + tx + cx;
            sp[e + 1] = x * R01 + y * R11 + z * R21 + ty + cy;
            sp[e + 2] = x * R02 + y * R12 + z * R22 + tz + cz;
        }
        __syncthreads();

        // Stage out: lane-contiguous float4 stores.
#pragma unroll
        for (int s = 0; s < 3; ++s) {
            o4[tid + BLOCK * s] = sp4[tid + BLOCK * s];
        }
        __syncthreads();   // protect sp/sc before next tile's staging writes
    }
}

extern "C" void kernel_launch(void* const* d_in, const int* in_sizes, int n_in,
                              void* d_out, int out_size, void* d_ws, size_t ws_size,
                              hipStream_t stream) {
    const float* pred   = (const float*)d_in[0];
    const float* cenp   = (const float*)d_in[1];
    const float* dofs   = (const float*)d_in[2];
    const float* ptrans = (const float*)d_in[3];
    float* out = (float*)d_out;

    int total_points = in_sizes[0] / 3;          // B*T*N = 4,194,304
    int n_tiles = total_points / TILE_PTS;       // 4096
    int grid = 2048;                             // 2 tiles per block, grid-stride

    tooth_assembler_kernel<<<grid, BLOCK, 0, stream>>>(pred, cenp, dofs, ptrans, out, n_tiles);
}